// Round 22
// baseline (241.900 us; speedup 1.0000x reference)
//
#include <hip/hip_runtime.h>

typedef unsigned short u16;
typedef __attribute__((ext_vector_type(8))) short bf16x8;
typedef __attribute__((ext_vector_type(4))) float f32x4;

#define AS1C(p) ((const __attribute__((address_space(1))) void*)(p))
#define AS3(p)  ((__attribute__((address_space(3))) void*)(p))

// s_barrier is NOT a compiler memory fence; CFENCE pins LDS/global ops.
// CFENCE does NOT drain hardware queues (R19): ds_write->barrier->ds_read
// needs __syncthreads().
#define CFENCE() asm volatile("" ::: "memory")

__device__ __forceinline__ u16 f2bf(float f) {
    unsigned u = __float_as_uint(f);
    u += 0x7fffu + ((u >> 16) & 1u);   // RTNE
    return (u16)(u >> 16);
}

// ---------------------------------------------------------------------------
// Fused prep: blocks [0,N): LayerNorm row -> bf16 A.
//             blocks [N,N+D): cast W_patch row -> bf16 W.
//             block  N+D:     class_emb + class_pos -> out row 0.
// Measured at HBM roofline (~48us).
// ---------------------------------------------------------------------------
__global__ __launch_bounds__(256) void prep_kernel(
    const float* __restrict__ x, const float* __restrict__ w,
    const float* __restrict__ b, const float* __restrict__ Wp,
    const float* __restrict__ ce, const float* __restrict__ cp,
    u16* __restrict__ A, u16* __restrict__ Wb, float* __restrict__ out,
    int N, int D, int K)
{
    const int blk = blockIdx.x;
    const int t = threadIdx.x;

    if (blk < N) {
        const float* xr = x + (size_t)blk * K;
        float4 v[3];
#pragma unroll
        for (int i = 0; i < 3; ++i)
            v[i] = *(const float4*)&xr[(i * 256 + t) * 4];

        float s = 0.f;
#pragma unroll
        for (int i = 0; i < 3; ++i) s += v[i].x + v[i].y + v[i].z + v[i].w;
#pragma unroll
        for (int off = 32; off; off >>= 1) s += __shfl_down(s, off);

        __shared__ float red[8];
        const int wid = t >> 6, lane = t & 63;
        if (lane == 0) red[wid] = s;
        __syncthreads();
        const float mu = (red[0] + red[1] + red[2] + red[3]) * (1.0f / 3072.0f);

        float sq = 0.f;
#pragma unroll
        for (int i = 0; i < 3; ++i) {
            float dx = v[i].x - mu, dy = v[i].y - mu, dz = v[i].z - mu, dw = v[i].w - mu;
            sq += dx * dx + dy * dy + dz * dz + dw * dw;
        }
#pragma unroll
        for (int off = 32; off; off >>= 1) sq += __shfl_down(sq, off);
        if (lane == 0) red[4 + wid] = sq;
        __syncthreads();
        const float var = (red[4] + red[5] + red[6] + red[7]) * (1.0f / 3072.0f);
        const float inv = rsqrtf(var + 1e-5f);

#pragma unroll
        for (int i = 0; i < 3; ++i) {
            const int j = (i * 256 + t) * 4;
            const float4 wv = *(const float4*)&w[j];
            const float4 bv = *(const float4*)&b[j];
            ushort4 o;
            o.x = f2bf((v[i].x - mu) * inv * wv.x + bv.x);
            o.y = f2bf((v[i].y - mu) * inv * wv.y + bv.y);
            o.z = f2bf((v[i].z - mu) * inv * wv.z + bv.z);
            o.w = f2bf((v[i].w - mu) * inv * wv.w + bv.w);
            *(ushort4*)&A[(size_t)blk * K + j] = o;
        }
    } else if (blk < N + D) {
        const int row = blk - N;
        const float* wr = Wp + (size_t)row * K;
#pragma unroll
        for (int i = 0; i < 3; ++i) {
            const int j = (i * 256 + t) * 4;
            const float4 v = *(const float4*)&wr[j];
            ushort4 o;
            o.x = f2bf(v.x); o.y = f2bf(v.y); o.z = f2bf(v.z); o.w = f2bf(v.w);
            *(ushort4*)&Wb[(size_t)row * K + j] = o;
        }
    } else {
#pragma unroll
        for (int i = 0; i < 4; ++i) {
            const int j = i * 256 + t;
            out[j] = ce[j] + cp[j];
        }
    }
}

// ---------------------------------------------------------------------------
// 256x256 bf16 GEMM, mfma_f32_16x16x32_bf16, 8 waves (2Mx4N), wave 128x64.
// R22 = R21 (B-reuse, minimal barriers Ph1/Ph4/Ph5/Ph8, counted vmcnt,
// 3-bit XOR swizzle, XCD swizzle, hardened epilogue) + INTRA-WAVE READ
// PREFETCH in the drift windows: within {Ph2,Ph3,Ph4} all staging targets
// the OTHER buffer, so the window's 16 ds_reads are issued eagerly and
// stream under the MFMA ladders (LDS pipe is the binding resource at ~2300
// cyc/tile vs MFMA ~600; R21 left it ~50% idle via read/MFMA alternation).
// In-order ds completion ledger (16 reads: r[4], hbB+s[8], u[4]):
//   Ph2 ladder: LGKM(11/10/9/8)  (r ready; 8+4 younger outstanding)
//   Ph3 ladder: LGKM(7/6/5/4)    (hbB+s ready; u outstanding)
//   Ph4 ladder: LGKM(3/2/1/0)
// vmcnt ledger and barrier positions identical to R18/R21 (verified).
// ---------------------------------------------------------------------------
#define STG_A(BUFOFS, R0, T_) \
    __builtin_amdgcn_global_load_lds(AS1C(aS + (size_t)(R0) * 3072 + (T_) * 64), \
                                     AS3(dA + (BUFOFS) + (R0) * 128), 16, 0, 0)
#define STG_B(BUFOFS, R0, T_) \
    __builtin_amdgcn_global_load_lds(AS1C(bS + (size_t)(R0) * 3072 + (T_) * 64), \
                                     AS3(dB + (BUFOFS) + (R0) * 128), 16, 0, 0)

#define MFMA16(d, a, b) d = __builtin_amdgcn_mfma_f32_16x16x32_bf16(a, b, d, 0, 0, 0)

#define LGKM_(N_) asm volatile("s_waitcnt lgkmcnt(" #N_ ")" ::: "memory"); \
                  __builtin_amdgcn_sched_barrier(0)
#define LGKM(N_) LGKM_(N_)

#define BARRIER() { __builtin_amdgcn_s_barrier(); CFENCE(); }
#define VMW_(N_) asm volatile("s_waitcnt vmcnt(" #N_ ")" ::: "memory")
#define VMW(N_) VMW_(N_)

// 4 B-frag reads into named regs.
#define RD_B(BUF, CK, H0, H1, H2, H3) \
    H0 = *(const bf16x8*)(L + (BUF) + bRowBase + 0 * 2048 + (CK)); \
    H1 = *(const bf16x8*)(L + (BUF) + bRowBase + 1 * 2048 + (CK)); \
    H2 = *(const bf16x8*)(L + (BUF) + bRowBase + 2 * 2048 + (CK)); \
    H3 = *(const bf16x8*)(L + (BUF) + bRowBase + 3 * 2048 + (CK))

// 4 A-frag reads (M-half MH) into named regs.
#define RD_A(BUF, MH, CK, P0, P1, P2, P3) \
    P0 = *(const bf16x8*)(L + (BUF) + aRowBase + (MH) * 8192 + 0 * 2048 + (CK)); \
    P1 = *(const bf16x8*)(L + (BUF) + aRowBase + (MH) * 8192 + 1 * 2048 + (CK)); \
    P2 = *(const bf16x8*)(L + (BUF) + aRowBase + (MH) * 8192 + 2 * 2048 + (CK)); \
    P3 = *(const bf16x8*)(L + (BUF) + aRowBase + (MH) * 8192 + 3 * 2048 + (CK))

// Laddered 16-MFMA block: group g gated on its A-frag via counted lgkm.
#define LADR(MH, A0, A1, A2, A3, H0, H1, H2, H3, W3, W2, W1, W0)                  \
    __builtin_amdgcn_s_setprio(1);                                                \
    LGKM(W3);                                                                     \
    MFMA16(acc[(MH)*4+0][0], A0, H0); MFMA16(acc[(MH)*4+0][1], A0, H1);           \
    MFMA16(acc[(MH)*4+0][2], A0, H2); MFMA16(acc[(MH)*4+0][3], A0, H3);           \
    LGKM(W2);                                                                     \
    MFMA16(acc[(MH)*4+1][0], A1, H0); MFMA16(acc[(MH)*4+1][1], A1, H1);           \
    MFMA16(acc[(MH)*4+1][2], A1, H2); MFMA16(acc[(MH)*4+1][3], A1, H3);           \
    LGKM(W1);                                                                     \
    MFMA16(acc[(MH)*4+2][0], A2, H0); MFMA16(acc[(MH)*4+2][1], A2, H1);           \
    MFMA16(acc[(MH)*4+2][2], A2, H2); MFMA16(acc[(MH)*4+2][3], A2, H3);           \
    LGKM(W0);                                                                     \
    MFMA16(acc[(MH)*4+3][0], A3, H0); MFMA16(acc[(MH)*4+3][1], A3, H1);           \
    MFMA16(acc[(MH)*4+3][2], A3, H2); MFMA16(acc[(MH)*4+3][3], A3, H3);           \
    __builtin_amdgcn_s_setprio(0)

__global__ __launch_bounds__(512, 2) void gemm_256_r22_kernel(
    const u16* __restrict__ A, const u16* __restrict__ W,
    const float* __restrict__ bbox, const float* __restrict__ Wpos,
    const float* __restrict__ bpos, float* __restrict__ out,
    int D)
{
    __shared__ __align__(16) char lds[131072];
    const char* L = (const char*)lds;
    const int K = 3072;
    const int NK = 48;                     // K / 64

    // XCD-bijective swizzle: 256 blocks, 8 XCDs, 32 contiguous tiles per XCD.
    const int bid = blockIdx.x;
    const int swb = (bid & 7) * 32 + (bid >> 3);
    const int bx = swb & 3;                // D/256 = 4
    const int by = swb >> 2;               // M/256 = 64
    const int brow = by * 256;
    const int bcol = bx * 256;

    const int t = threadIdx.x;
    const int wid = t >> 6, lane = t & 63;
    const int wm = wid >> 2;               // 0..1
    const int wn = wid & 3;                // 0..3
    const int fr = lane & 15;
    const int kq16 = ((lane >> 4) & 3) * 16;   // 16B quarter within 64B k-half
    const int xorb = (fr & 7) << 4;            // byte ^= (row&7)<<4
    const int aRowBase = (wm * 128 + fr) * 128;
    const int bRowBase = 32768 + (wn * 64 + fr) * 128;
    const int ckh0 = (0  + kq16) ^ xorb;
    const int ckh1 = (64 + kq16) ^ xorb;

    // staging: linear LDS dest (t*16 B), pre-swizzled global source.
    const int srow = t >> 3;
    const int scol = ((t & 7) ^ ((t >> 3) & 7)) * 8;   // bf16 units
    const u16* aS = A + (size_t)(brow + srow) * K + scol;
    const u16* bS = W + (size_t)(bcol + srow) * K + scol;
    char* dA = (char*)lds + t * 16;
    char* dB = (char*)lds + 32768 + t * 16;

    f32x4 acc[8][4] = {};
    bf16x8 hbA0, hbA1, hbA2, hbA3;         // B-frags for ck-half 0
    bf16x8 hbB0, hbB1, hbB2, hbB3;         // B-frags for ck-half 1
    bf16x8 q0, q1, q2, q3;                 // Ph1 A-frags (MH0, ckh0)
    bf16x8 r0, r1, r2, r3;                 // Ph2 A-frags (MH1, ckh0)
    bf16x8 s0, s1, s2, s3;                 // Ph3 A-frags (MH0, ckh1)
    bf16x8 u0, u1, u2, u3;                 // Ph4 A-frags (MH1, ckh1)

    // prologue: tile0 full (8 STG) -> buf0; drain; barrier.
    STG_B(0, 0, 0);   STG_B(0, 64, 0);  STG_B(0, 128, 0); STG_B(0, 192, 0);
    STG_A(0, 0, 0);   STG_A(0, 128, 0); STG_A(0, 64, 0);  STG_A(0, 192, 0);
    VMW(0);
    BARRIER();

    for (int T = 0; T < NK; T += 2) {
        const bool more = (T + 2) < NK;

        // ---------------- tile T in buf0 ----------------
        // Ph1 (MH0, ckh0): 8 reads, ladder, publish A(T)MH1.
        RD_B(0, ckh0, hbA0, hbA1, hbA2, hbA3);
        RD_A(0, 0, ckh0, q0, q1, q2, q3);
        STG_B(65536, 0, T + 1); STG_B(65536, 64, T + 1);
        LADR(0, q0, q1, q2, q3, hbA0, hbA1, hbA2, hbA3, 3, 2, 1, 0);
        VMW(2);
        BARRIER();
        // window Ph2..Ph4: all stages -> buf1; reads <- buf0; stream reads.
        RD_A(0, 1, ckh0, r0, r1, r2, r3);            // Ph2 reads (4)
        RD_B(0, ckh1, hbB0, hbB1, hbB2, hbB3);       // Ph3 reads (8)
        RD_A(0, 0, ckh1, s0, s1, s2, s3);
        STG_B(65536, 128, T + 1); STG_B(65536, 192, T + 1);
        LADR(1, r0, r1, r2, r3, hbA0, hbA1, hbA2, hbA3, 11, 10, 9, 8);   // Ph2
        RD_A(0, 1, ckh1, u0, u1, u2, u3);            // Ph4 reads (4)
        STG_A(65536, 0, T + 1); STG_A(65536, 128, T + 1);
        LADR(0, s0, s1, s2, s3, hbB0, hbB1, hbB2, hbB3, 7, 6, 5, 4);     // Ph3
        STG_A(65536, 64, T + 1); STG_A(65536, 192, T + 1);
        LADR(1, u0, u1, u2, u3, hbB0, hbB1, hbB2, hbB3, 3, 2, 1, 0);     // Ph4
        VMW(2);
        BARRIER();

        // ---------------- tile T+1 in buf1 ----------------
        // Ph5 (MH0, ckh0): publish A(T+1)MH1.
        RD_B(65536, ckh0, hbA0, hbA1, hbA2, hbA3);
        RD_A(65536, 0, ckh0, q0, q1, q2, q3);
        if (more) { STG_B(0, 0, T + 2); STG_B(0, 64, T + 2); }
        LADR(0, q0, q1, q2, q3, hbA0, hbA1, hbA2, hbA3, 3, 2, 1, 0);
        if (more) { VMW(2); } else { VMW(0); }
        BARRIER();
        // window Ph6..Ph8: stages -> buf0; reads <- buf1.
        RD_A(65536, 1, ckh0, r0, r1, r2, r3);
        RD_B(65536, ckh1, hbB0, hbB1, hbB2, hbB3);
        RD_A(65536, 0, ckh1, s0, s1, s2, s3);
        if (more) { STG_B(0, 128, T + 2); STG_B(0, 192, T + 2); }
        LADR(1, r0, r1, r2, r3, hbA0, hbA1, hbA2, hbA3, 11, 10, 9, 8);   // Ph6
        RD_A(65536, 1, ckh1, u0, u1, u2, u3);
        if (more) { STG_A(0, 0, T + 2); STG_A(0, 128, T + 2); }
        LADR(0, s0, s1, s2, s3, hbB0, hbB1, hbB2, hbB3, 7, 6, 5, 4);     // Ph7
        if (more) { STG_A(0, 64, T + 2); STG_A(0, 192, T + 2); }
        LADR(1, u0, u1, u2, u3, hbB0, hbB1, hbB2, hbB3, 3, 2, 1, 0);     // Ph8
        if (more) { VMW(2); }
        BARRIER();
    }

    // ---------------- epilogue: LDS transpose -> coalesced float4 stores ------
    // 16x16 C/D layout: col = lane&15, row = (lane>>4)*4 + r.
    // __syncthreads() handoffs (lgkmcnt(0) drain) per R19 lesson.
    float* Lf = (float*)lds;
    const int r4 = ((lane >> 4) & 3) * 4;   // row sub-offset within fragment
    const int cg = bcol + lane * 4;         // 4 output cols per lane (coalesced)

    float4 wpv[4];
    float bpv[4];
#pragma unroll
    for (int j = 0; j < 4; ++j) {
        wpv[j] = *(const float4*)&Wpos[(cg + j) * 4];
        bpv[j] = bpos[cg + j];
    }

#pragma unroll
    for (int c = 0; c < 4; ++c) {           // chunk c: block rows {c*32..+32} u {128+c*32..+32}
        __syncthreads();
#pragma unroll
        for (int q = 0; q < 2; ++q) {       // frag mi = c*2+q
#pragma unroll
            for (int n = 0; n < 4; ++n) {
                const f32x4 v = acc[c * 2 + q][n];
                const int col = wn * 64 + n * 16 + fr;
#pragma unroll
                for (int r = 0; r < 4; ++r)
                    Lf[(wm * 32 + q * 16 + r4 + r) * 256 + col] = v[r];
            }
        }
        __syncthreads();
#pragma unroll
        for (int i = 0; i < 8; ++i) {
            const int lrow = wid + 8 * i;                     // 0..63
            const int gr = brow + (lrow >> 5) * 128 + c * 32 + (lrow & 31);
            const float4 v = *(const float4*)&Lf[lrow * 256 + lane * 4];
            const float4 bb = *(const float4*)&bbox[(size_t)gr * 4];
            float4 o;
            o.x = v.x + bpv[0] + bb.x * wpv[0].x + bb.y * wpv[0].y + bb.z * wpv[0].z + bb.w * wpv[0].w;
            o.y = v.y + bpv[1] + bb.x * wpv[1].x + bb.y * wpv[1].y + bb.z * wpv[1].z + bb.w * wpv[1].w;
            o.z = v.z + bpv[2] + bb.x * wpv[2].x + bb.y * wpv[2].y + bb.z * wpv[2].z + bb.w * wpv[2].w;
            o.w = v.w + bpv[3] + bb.x * wpv[3].x + bb.y * wpv[3].y + bb.z * wpv[3].z + bb.w * wpv[3].w;
            *(float4*)&out[(size_t)(gr + 1) * D + cg] = o;
        }
    }
}

// ---------------------------------------------------------------------------
extern "C" void kernel_launch(void* const* d_in, const int* in_sizes, int n_in,
                              void* d_out, int out_size, void* d_ws, size_t ws_size,
                              hipStream_t stream)
{
    const float* patches   = (const float*)d_in[0];
    const float* bbox      = (const float*)d_in[1];
    const float* ln1_w     = (const float*)d_in[2];
    const float* ln1_b     = (const float*)d_in[3];
    const float* W_patch   = (const float*)d_in[4];
    const float* class_emb = (const float*)d_in[5];
    const float* W_pos     = (const float*)d_in[6];
    const float* b_pos     = (const float*)d_in[7];
    const float* class_pos = (const float*)d_in[8];
    float* out = (float*)d_out;

    const int N = in_sizes[1] / 4;   // 16384
    const int K = in_sizes[2];       // 3072
    const int D = in_sizes[7];       // 1024

    u16* Abf = (u16*)d_ws;                       // [N,K] bf16
    u16* Wbf = Abf + (size_t)N * K;              // [D,K] bf16

    prep_kernel<<<N + D + 1, 256, 0, stream>>>(patches, ln1_w, ln1_b, W_patch,
                                               class_emb, class_pos, Abf, Wbf, out,
                                               N, D, K);

    const int nblk = (N / 256) * (D / 256);      // 64 * 4 = 256
    gemm_256_r22_kernel<<<nblk, 512, 0, stream>>>(Abf, Wbf, bbox, W_pos, b_pos, out, D);
}

// Round 23
// 150.594 us; speedup vs baseline: 1.6063x; 1.6063x over previous
//
#include <hip/hip_runtime.h>

typedef unsigned short u16;
typedef __attribute__((ext_vector_type(8))) short bf16x8;
typedef __attribute__((ext_vector_type(4))) float f32x4;

#define AS1C(p) ((const __attribute__((address_space(1))) void*)(p))
#define AS3(p)  ((__attribute__((address_space(3))) void*)(p))

// s_barrier is NOT a compiler memory fence; CFENCE pins LDS/global ops.
// CFENCE does NOT drain hardware queues (R19): ds_write->barrier->ds_read
// needs __syncthreads().
#define CFENCE() asm volatile("" ::: "memory")

__device__ __forceinline__ u16 f2bf(float f) {
    unsigned u = __float_as_uint(f);
    u += 0x7fffu + ((u >> 16) & 1u);   // RTNE
    return (u16)(u >> 16);
}

// ---------------------------------------------------------------------------
// Fused prep: blocks [0,N): LayerNorm row -> bf16 A.
//             blocks [N,N+D): cast W_patch row -> bf16 W.
//             block  N+D:     class_emb + class_pos -> out row 0.
// Measured at HBM roofline (~48us).
// ---------------------------------------------------------------------------
__global__ __launch_bounds__(256) void prep_kernel(
    const float* __restrict__ x, const float* __restrict__ w,
    const float* __restrict__ b, const float* __restrict__ Wp,
    const float* __restrict__ ce, const float* __restrict__ cp,
    u16* __restrict__ A, u16* __restrict__ Wb, float* __restrict__ out,
    int N, int D, int K)
{
    const int blk = blockIdx.x;
    const int t = threadIdx.x;

    if (blk < N) {
        const float* xr = x + (size_t)blk * K;
        float4 v[3];
#pragma unroll
        for (int i = 0; i < 3; ++i)
            v[i] = *(const float4*)&xr[(i * 256 + t) * 4];

        float s = 0.f;
#pragma unroll
        for (int i = 0; i < 3; ++i) s += v[i].x + v[i].y + v[i].z + v[i].w;
#pragma unroll
        for (int off = 32; off; off >>= 1) s += __shfl_down(s, off);

        __shared__ float red[8];
        const int wid = t >> 6, lane = t & 63;
        if (lane == 0) red[wid] = s;
        __syncthreads();
        const float mu = (red[0] + red[1] + red[2] + red[3]) * (1.0f / 3072.0f);

        float sq = 0.f;
#pragma unroll
        for (int i = 0; i < 3; ++i) {
            float dx = v[i].x - mu, dy = v[i].y - mu, dz = v[i].z - mu, dw = v[i].w - mu;
            sq += dx * dx + dy * dy + dz * dz + dw * dw;
        }
#pragma unroll
        for (int off = 32; off; off >>= 1) sq += __shfl_down(sq, off);
        if (lane == 0) red[4 + wid] = sq;
        __syncthreads();
        const float var = (red[4] + red[5] + red[6] + red[7]) * (1.0f / 3072.0f);
        const float inv = rsqrtf(var + 1e-5f);

#pragma unroll
        for (int i = 0; i < 3; ++i) {
            const int j = (i * 256 + t) * 4;
            const float4 wv = *(const float4*)&w[j];
            const float4 bv = *(const float4*)&b[j];
            ushort4 o;
            o.x = f2bf((v[i].x - mu) * inv * wv.x + bv.x);
            o.y = f2bf((v[i].y - mu) * inv * wv.y + bv.y);
            o.z = f2bf((v[i].z - mu) * inv * wv.z + bv.z);
            o.w = f2bf((v[i].w - mu) * inv * wv.w + bv.w);
            *(ushort4*)&A[(size_t)blk * K + j] = o;
        }
    } else if (blk < N + D) {
        const int row = blk - N;
        const float* wr = Wp + (size_t)row * K;
#pragma unroll
        for (int i = 0; i < 3; ++i) {
            const int j = (i * 256 + t) * 4;
            const float4 v = *(const float4*)&wr[j];
            ushort4 o;
            o.x = f2bf(v.x); o.y = f2bf(v.y); o.z = f2bf(v.z); o.w = f2bf(v.w);
            *(ushort4*)&Wb[(size_t)row * K + j] = o;
        }
    } else {
#pragma unroll
        for (int i = 0; i < 4; ++i) {
            const int j = i * 256 + t;
            out[j] = ce[j] + cp[j];
        }
    }
}

// ---------------------------------------------------------------------------
// 256x256 bf16 GEMM, mfma_f32_16x16x32_bf16, 8 waves (2Mx4N), wave 128x64.
// FINAL (= R21, best hardened, 149.9us total): B-fragment reuse (24 LDS
// reads/tile/wave), per-A-frag lgkm ladder, counted vmcnt with verified
// ledger, minimal load-bearing barriers (Ph1/Ph4/Ph5/Ph8) with drift
// windows, 3-bit XOR swizzle both-sides, XCD-bijective block swizzle,
// __syncthreads()-hardened epilogue. Bank conflicts 5.2e5 (18x below the
// lockstep variants). GEMM ~1060 TF; prep at ~88% HBM BW.
// ---------------------------------------------------------------------------
#define STG_A(BUFOFS, R0, T_) \
    __builtin_amdgcn_global_load_lds(AS1C(aS + (size_t)(R0) * 3072 + (T_) * 64), \
                                     AS3(dA + (BUFOFS) + (R0) * 128), 16, 0, 0)
#define STG_B(BUFOFS, R0, T_) \
    __builtin_amdgcn_global_load_lds(AS1C(bS + (size_t)(R0) * 3072 + (T_) * 64), \
                                     AS3(dB + (BUFOFS) + (R0) * 128), 16, 0, 0)

#define MFMA16(d, a, b) d = __builtin_amdgcn_mfma_f32_16x16x32_bf16(a, b, d, 0, 0, 0)

#define LGKM(N_) asm volatile("s_waitcnt lgkmcnt(" #N_ ")" ::: "memory"); \
                 __builtin_amdgcn_sched_barrier(0)

#define BARRIER() { __builtin_amdgcn_s_barrier(); CFENCE(); }

// MFMA block for M-half MH using held B-frags hb0..hb3 and A-frags a0..a3.
#define MFMA_LADDER(MH, a0, a1, a2, a3)                                           \
    LGKM(3);                                                                      \
    MFMA16(acc[(MH)*4+0][0], a0, hb0); MFMA16(acc[(MH)*4+0][1], a0, hb1);         \
    MFMA16(acc[(MH)*4+0][2], a0, hb2); MFMA16(acc[(MH)*4+0][3], a0, hb3);         \
    LGKM(2);                                                                      \
    MFMA16(acc[(MH)*4+1][0], a1, hb0); MFMA16(acc[(MH)*4+1][1], a1, hb1);         \
    MFMA16(acc[(MH)*4+1][2], a1, hb2); MFMA16(acc[(MH)*4+1][3], a1, hb3);         \
    LGKM(1);                                                                      \
    MFMA16(acc[(MH)*4+2][0], a2, hb0); MFMA16(acc[(MH)*4+2][1], a2, hb1);         \
    MFMA16(acc[(MH)*4+2][2], a2, hb2); MFMA16(acc[(MH)*4+2][3], a2, hb3);         \
    LGKM(0);                                                                      \
    MFMA16(acc[(MH)*4+3][0], a3, hb0); MFMA16(acc[(MH)*4+3][1], a3, hb1);         \
    MFMA16(acc[(MH)*4+3][2], a3, hb2); MFMA16(acc[(MH)*4+3][3], a3, hb3)

// Phase mh0: read 4 B-frags (-> held regs) + 4 A-frags (8 reads), MFMA mh0.
// TAIL = trailing sync (vmcnt and/or barrier), placed by the caller.
#define PHB(BUF, KH, STG, TAIL) do {                                              \
    const char* Ab = L + (BUF) + aRowBase;                                        \
    const char* Bb = L + (BUF) + bRowBase;                                        \
    const int ck = (KH) ? ckh1 : ckh0;                                            \
    hb0 = *(const bf16x8*)(Bb + 0 * 2048 + ck);                                   \
    hb1 = *(const bf16x8*)(Bb + 1 * 2048 + ck);                                   \
    hb2 = *(const bf16x8*)(Bb + 2 * 2048 + ck);                                   \
    hb3 = *(const bf16x8*)(Bb + 3 * 2048 + ck);                                   \
    bf16x8 a0 = *(const bf16x8*)(Ab + 0 * 2048 + ck);                             \
    bf16x8 a1 = *(const bf16x8*)(Ab + 1 * 2048 + ck);                             \
    bf16x8 a2 = *(const bf16x8*)(Ab + 2 * 2048 + ck);                             \
    bf16x8 a3 = *(const bf16x8*)(Ab + 3 * 2048 + ck);                             \
    STG;                                                                          \
    __builtin_amdgcn_s_setprio(1);                                                \
    MFMA_LADDER(0, a0, a1, a2, a3);                                               \
    __builtin_amdgcn_s_setprio(0);                                                \
    TAIL;                                                                         \
} while (0)

// Phase mh1: B held in regs from the paired PHB; read only 4 A-frags.
#define PHA(BUF, KH, STG, TAIL) do {                                              \
    const char* Ab = L + (BUF) + aRowBase + 8192;                                 \
    const int ck = (KH) ? ckh1 : ckh0;                                            \
    bf16x8 a0 = *(const bf16x8*)(Ab + 0 * 2048 + ck);                             \
    bf16x8 a1 = *(const bf16x8*)(Ab + 1 * 2048 + ck);                             \
    bf16x8 a2 = *(const bf16x8*)(Ab + 2 * 2048 + ck);                             \
    bf16x8 a3 = *(const bf16x8*)(Ab + 3 * 2048 + ck);                             \
    STG;                                                                          \
    __builtin_amdgcn_s_setprio(1);                                                \
    MFMA_LADDER(1, a0, a1, a2, a3);                                               \
    __builtin_amdgcn_s_setprio(0);                                                \
    TAIL;                                                                         \
} while (0)

#define VMW(N_) asm volatile("s_waitcnt vmcnt(" #N_ ")" ::: "memory")

__global__ __launch_bounds__(512, 2) void gemm_256_final_kernel(
    const u16* __restrict__ A, const u16* __restrict__ W,
    const float* __restrict__ bbox, const float* __restrict__ Wpos,
    const float* __restrict__ bpos, float* __restrict__ out,
    int D)
{
    __shared__ __align__(16) char lds[131072];
    const char* L = (const char*)lds;
    const int K = 3072;
    const int NK = 48;                     // K / 64

    // XCD-bijective swizzle: 256 blocks, 8 XCDs, 32 contiguous tiles per XCD.
    const int bid = blockIdx.x;
    const int swb = (bid & 7) * 32 + (bid >> 3);
    const int bx = swb & 3;                // D/256 = 4
    const int by = swb >> 2;               // M/256 = 64
    const int brow = by * 256;
    const int bcol = bx * 256;

    const int t = threadIdx.x;
    const int wid = t >> 6, lane = t & 63;
    const int wm = wid >> 2;               // 0..1
    const int wn = wid & 3;                // 0..3
    const int fr = lane & 15;
    const int kq16 = ((lane >> 4) & 3) * 16;   // 16B quarter within 64B k-half
    const int xorb = (fr & 7) << 4;            // byte ^= (row&7)<<4
    const int aRowBase = (wm * 128 + fr) * 128;
    const int bRowBase = 32768 + (wn * 64 + fr) * 128;
    const int ckh0 = (0  + kq16) ^ xorb;
    const int ckh1 = (64 + kq16) ^ xorb;

    // staging: linear LDS dest (t*16 B), pre-swizzled global source.
    const int srow = t >> 3;
    const int scol = ((t & 7) ^ ((t >> 3) & 7)) * 8;   // bf16 units
    const u16* aS = A + (size_t)(brow + srow) * K + scol;
    const u16* bS = W + (size_t)(bcol + srow) * K + scol;
    char* dA = (char*)lds + t * 16;
    char* dB = (char*)lds + 32768 + t * 16;

    f32x4 acc[8][4] = {};
    bf16x8 hb0, hb1, hb2, hb3;             // held B-frags (shared mh0/mh1)

    // prologue: tile0 full (8 STG) -> buf0; drain; barrier.
    STG_B(0, 0, 0);   STG_B(0, 64, 0);  STG_B(0, 128, 0); STG_B(0, 192, 0);
    STG_A(0, 0, 0);   STG_A(0, 128, 0); STG_A(0, 64, 0);  STG_A(0, 192, 0);
    VMW(0);
    BARRIER();

    for (int T = 0; T < NK; T += 2) {
        const bool more = (T + 2) < NK;
        // tile T in buf0
        PHB(0, 0, { STG_B(65536, 0, T + 1); STG_B(65536, 64, T + 1); },
            { VMW(2); BARRIER(); });                              // Ph1 (pub A(T)MH1)
        PHA(0, 0, { STG_B(65536, 128, T + 1); STG_B(65536, 192, T + 1); },
            ((void)0));                                           // Ph2 (drift)
        PHB(0, 1, { STG_A(65536, 0, T + 1); STG_A(65536, 128, T + 1); },
            ((void)0));                                           // Ph3 (drift)
        PHA(0, 1, { STG_A(65536, 64, T + 1); STG_A(65536, 192, T + 1); },
            { VMW(2); BARRIER(); });                              // Ph4 (pub B+A0(T+1))
        // tile T+1 in buf1
        PHB(65536, 0, { if (more) { STG_B(0, 0, T + 2); STG_B(0, 64, T + 2); } },
            { if (more) { VMW(2); } else { VMW(0); } BARRIER(); }); // Ph5 (pub A(T+1)MH1)
        PHA(65536, 0, { if (more) { STG_B(0, 128, T + 2); STG_B(0, 192, T + 2); } },
            ((void)0));                                           // Ph6 (drift)
        PHB(65536, 1, { if (more) { STG_A(0, 0, T + 2); STG_A(0, 128, T + 2); } },
            ((void)0));                                           // Ph7 (drift)
        PHA(65536, 1, { if (more) { STG_A(0, 64, T + 2); STG_A(0, 192, T + 2); } },
            { if (more) { VMW(2); } BARRIER(); });                // Ph8 (pub B+A0(T+2))
    }

    // ---------------- epilogue: LDS transpose -> coalesced float4 stores ------
    // 16x16 C/D layout: col = lane&15, row = (lane>>4)*4 + r.
    // __syncthreads() handoffs (lgkmcnt(0) drain) per R19 lesson.
    float* Lf = (float*)lds;
    const int r4 = ((lane >> 4) & 3) * 4;   // row sub-offset within fragment
    const int cg = bcol + lane * 4;         // 4 output cols per lane (coalesced)

    float4 wpv[4];
    float bpv[4];
#pragma unroll
    for (int j = 0; j < 4; ++j) {
        wpv[j] = *(const float4*)&Wpos[(cg + j) * 4];
        bpv[j] = bpos[cg + j];
    }

#pragma unroll
    for (int c = 0; c < 4; ++c) {           // chunk c: block rows {c*32..+32} u {128+c*32..+32}
        __syncthreads();
#pragma unroll
        for (int q = 0; q < 2; ++q) {       // frag mi = c*2+q
#pragma unroll
            for (int n = 0; n < 4; ++n) {
                const f32x4 v = acc[c * 2 + q][n];
                const int col = wn * 64 + n * 16 + fr;
#pragma unroll
                for (int r = 0; r < 4; ++r)
                    Lf[(wm * 32 + q * 16 + r4 + r) * 256 + col] = v[r];
            }
        }
        __syncthreads();
#pragma unroll
        for (int i = 0; i < 8; ++i) {
            const int lrow = wid + 8 * i;                     // 0..63
            const int gr = brow + (lrow >> 5) * 128 + c * 32 + (lrow & 31);
            const float4 v = *(const float4*)&Lf[lrow * 256 + lane * 4];
            const float4 bb = *(const float4*)&bbox[(size_t)gr * 4];
            float4 o;
            o.x = v.x + bpv[0] + bb.x * wpv[0].x + bb.y * wpv[0].y + bb.z * wpv[0].z + bb.w * wpv[0].w;
            o.y = v.y + bpv[1] + bb.x * wpv[1].x + bb.y * wpv[1].y + bb.z * wpv[1].z + bb.w * wpv[1].w;
            o.z = v.z + bpv[2] + bb.x * wpv[2].x + bb.y * wpv[2].y + bb.z * wpv[2].z + bb.w * wpv[2].w;
            o.w = v.w + bpv[3] + bb.x * wpv[3].x + bb.y * wpv[3].y + bb.z * wpv[3].z + bb.w * wpv[3].w;
            *(float4*)&out[(size_t)(gr + 1) * D + cg] = o;
        }
    }
}

// ---------------------------------------------------------------------------
extern "C" void kernel_launch(void* const* d_in, const int* in_sizes, int n_in,
                              void* d_out, int out_size, void* d_ws, size_t ws_size,
                              hipStream_t stream)
{
    const float* patches   = (const float*)d_in[0];
    const float* bbox      = (const float*)d_in[1];
    const float* ln1_w     = (const float*)d_in[2];
    const float* ln1_b     = (const float*)d_in[3];
    const float* W_patch   = (const float*)d_in[4];
    const float* class_emb = (const float*)d_in[5];
    const float* W_pos     = (const float*)d_in[6];
    const float* b_pos     = (const float*)d_in[7];
    const float* class_pos = (const float*)d_in[8];
    float* out = (float*)d_out;

    const int N = in_sizes[1] / 4;   // 16384
    const int K = in_sizes[2];       // 3072
    const int D = in_sizes[7];       // 1024

    u16* Abf = (u16*)d_ws;                       // [N,K] bf16
    u16* Wbf = Abf + (size_t)N * K;              // [D,K] bf16

    prep_kernel<<<N + D + 1, 256, 0, stream>>>(patches, ln1_w, ln1_b, W_patch,
                                               class_emb, class_pos, Abf, Wbf, out,
                                               N, D, K);

    const int nblk = (N / 256) * (D / 256);      // 64 * 4 = 256
    gemm_256_final_kernel<<<nblk, 512, 0, stream>>>(Abf, Wbf, bbox, W_pos, b_pos, out, D);
}